// Round 2
// baseline (2539.408 us; speedup 1.0000x reference)
//
#include <hip/hip_runtime.h>
#include <hip/hip_bf16.h>

#define N_NODES 100000
#define N_EDGES 3200000
#define N_GRAPHS 64

__device__ __forceinline__ void atomAddF(float* p, float v) {
    unsafeAtomicAdd(p, v);  // HW global_atomic_add_f32
}

// ---------------- degree / norm precompute ----------------
__global__ void k_count(const int* __restrict__ dst, int* __restrict__ deg) {
    int e = blockIdx.x * 256 + threadIdx.x;
    if (e < N_EDGES) atomicAdd(&deg[dst[e]], 1);
}

__global__ void k_dinv(const int* __restrict__ deg, float* __restrict__ dinv) {
    int i = blockIdx.x * 256 + threadIdx.x;
    if (i < N_NODES) dinv[i] = rsqrtf((float)deg[i] + 1.0f);
}

__global__ void k_coef(const int* __restrict__ src, const int* __restrict__ dst,
                       const float* __restrict__ dinv, float* __restrict__ coef) {
    int e = blockIdx.x * 256 + threadIdx.x;
    if (e < N_EDGES) coef[e] = dinv[src[e]] * dinv[dst[e]];
}

// ---------------- propagate: out = Ahat * in  (width 2^LOGW) ----------------
// init: out[n,d] = in[n,d] * dinv[n]^2   (self-loop term)
template<int LOGW>
__global__ void k_prop_init(const float* __restrict__ in, const float* __restrict__ dinv,
                            float* __restrict__ out) {
    int idx = blockIdx.x * 256 + threadIdx.x;   // exact grid
    int n = idx >> LOGW;
    float di = dinv[n];
    out[idx] = in[idx] * di * di;
}

// edges: out[dst,d] += in[src,d] * coef[e]
template<int LOGW>
__global__ void k_prop_edge(const int* __restrict__ src, const int* __restrict__ dst,
                            const float* __restrict__ coef, const float* __restrict__ in,
                            float* __restrict__ agg) {
    int idx = blockIdx.x * 256 + threadIdx.x;   // exact grid: E<<LOGW
    int e = idx >> LOGW;
    int d = idx & ((1 << LOGW) - 1);
    int s = src[e];
    int t = dst[e];
    atomAddF(&agg[(t << LOGW) + d], in[(s << LOGW) + d] * coef[e]);
}

// ---------------- dense: two-branch small matmul ----------------
// out[n, d<H]      = act( sum_k in[n, A_OFF+k] * Wa[k,d]  (+ ba[d]) )
// out[n, H<=d<2H]  = act( sum_k in[n, B_OFF+k] * Wb[k,dd] (+ bb[dd]) )
template<int IN_W, int OUT_HALF, int A_OFF, int A_W, int B_OFF, bool BR>
__global__ void k_dense(const float* __restrict__ in,
                        const float* __restrict__ Wa, const float* __restrict__ ba,
                        const float* __restrict__ Wb, const float* __restrict__ bb,
                        float* __restrict__ out) {
    __shared__ float sWa[A_W * OUT_HALF];
    __shared__ float sWb[A_W * OUT_HALF];
    __shared__ float sba[OUT_HALF];
    __shared__ float sbb[OUT_HALF];
    for (int t = threadIdx.x; t < A_W * OUT_HALF; t += 256) {
        sWa[t] = Wa[t];
        sWb[t] = Wb[t];
    }
    if (BR && threadIdx.x < OUT_HALF) {
        sba[threadIdx.x] = ba[threadIdx.x];
        sbb[threadIdx.x] = bb[threadIdx.x];
    }
    __syncthreads();
    const int OUT2 = 2 * OUT_HALF;
    int idx = blockIdx.x * 256 + threadIdx.x;   // exact grid: N*OUT2
    int n = idx / OUT2;
    int d = idx % OUT2;
    bool isB = d >= OUT_HALF;
    int dd = isB ? d - OUT_HALF : d;
    int ko = isB ? B_OFF : A_OFF;
    const float* sW = isB ? sWb : sWa;
    float acc = BR ? (isB ? sbb[dd] : sba[dd]) : 0.0f;
    const float* row = in + n * IN_W;
    #pragma unroll
    for (int k = 0; k < A_W; ++k)
        acc += row[ko + k] * sW[k * OUT_HALF + dd];
    out[idx] = BR ? fmaxf(acc, 0.0f) : acc;
}

// h1 = relu(aggregated + bias), width 32 (bias halves b1m|b1l)
__global__ void k_biasrelu32(const float* __restrict__ in,
                             const float* __restrict__ ba, const float* __restrict__ bb,
                             float* __restrict__ out) {
    int idx = blockIdx.x * 256 + threadIdx.x;   // exact: N*32
    int d = idx & 31;
    float b = (d < 16) ? ba[d] : bb[d - 16];
    out[idx] = fmaxf(in[idx] + b, 0.0f);
}

// ---------------- pooling / reparam ----------------
__global__ void k_cnt(const int* __restrict__ batch, int* __restrict__ cnt) {
    int i = blockIdx.x * 256 + threadIdx.x;
    if (i < N_NODES) atomicAdd(&cnt[batch[i]], 1);
}

__global__ void k_pool(const float* __restrict__ h3, const int* __restrict__ batch,
                       float* __restrict__ pool) {
    int idx = blockIdx.x * 256 + threadIdx.x;   // exact: N*128
    int n = idx >> 7;
    int d = idx & 127;
    atomAddF(&pool[batch[n] * 128 + d], h3[idx]);
}

__global__ void k_final(const float* __restrict__ pool, const int* __restrict__ cnt,
                        const float* __restrict__ eps, float* __restrict__ zbuf,
                        float* __restrict__ out_mu, float* __restrict__ out_lv) {
    int idx = blockIdx.x * 256 + threadIdx.x;   // 4096 threads
    int g = idx >> 6;
    int k = idx & 63;
    float c = fmaxf((float)cnt[g], 1.0f);
    float mu = pool[g * 128 + k] / c;
    float lv = pool[g * 128 + 64 + k] / c;
    zbuf[idx] = mu + eps[idx] * __expf(0.5f * lv);
    out_mu[idx] = mu;
    out_lv[idx] = lv;
}

// ---------------- decode: sigmoid(z @ Wfc + bfc), z:[64,64], Wfc:[64,160000] --------
__global__ void __launch_bounds__(256) k_decode(const float* __restrict__ zbuf,
                                                const float* __restrict__ Wfc,
                                                const float* __restrict__ bfc,
                                                float* __restrict__ out) {
    __shared__ float sz[64 * 64];
    for (int t = threadIdx.x; t < 4096; t += 256) sz[t] = zbuf[t];
    __syncthreads();
    int j = blockIdx.x * 256 + threadIdx.x;     // 625 blocks exact -> 160000
    float bias = bfc[j];
    float acc[64];
    #pragma unroll
    for (int g = 0; g < 64; ++g) acc[g] = bias;
    #pragma unroll 4
    for (int k4 = 0; k4 < 16; ++k4) {
        float w0 = Wfc[(k4 * 4 + 0) * 160000 + j];
        float w1 = Wfc[(k4 * 4 + 1) * 160000 + j];
        float w2 = Wfc[(k4 * 4 + 2) * 160000 + j];
        float w3 = Wfc[(k4 * 4 + 3) * 160000 + j];
        #pragma unroll
        for (int g = 0; g < 64; ++g) {
            float4 zv = *(const float4*)&sz[g * 64 + k4 * 4];
            acc[g] = fmaf(zv.x, w0, acc[g]);
            acc[g] = fmaf(zv.y, w1, acc[g]);
            acc[g] = fmaf(zv.z, w2, acc[g]);
            acc[g] = fmaf(zv.w, w3, acc[g]);
        }
    }
    #pragma unroll
    for (int g = 0; g < 64; ++g) {
        float s = 1.0f / (1.0f + __expf(-acc[g]));
        out[g * 160000 + j] = s;
    }
}

extern "C" void kernel_launch(void* const* d_in, const int* in_sizes, int n_in,
                              void* d_out, int out_size, void* d_ws, size_t ws_size,
                              hipStream_t stream) {
    const float* x     = (const float*)d_in[0];
    const int*   ei    = (const int*)d_in[1];
    const int*   batch = (const int*)d_in[2];
    const float *W1m = (const float*)d_in[3],  *b1m = (const float*)d_in[4];
    const float *W2m = (const float*)d_in[5],  *b2m = (const float*)d_in[6];
    const float *W3m = (const float*)d_in[7],  *b3m = (const float*)d_in[8];
    const float *W1l = (const float*)d_in[9],  *b1l = (const float*)d_in[10];
    const float *W2l = (const float*)d_in[11], *b2l = (const float*)d_in[12];
    const float *W3l = (const float*)d_in[13], *b3l = (const float*)d_in[14];
    const float *Wfc = (const float*)d_in[15], *bfc = (const float*)d_in[16];
    const float *eps = (const float*)d_in[17];

    const int* srcv = ei;
    const int* dstv = ei + N_EDGES;

    char* w = (char*)d_ws;
    auto alloc = [&](size_t bytes) -> char* {
        char* p = w;
        w += (bytes + 255) & ~(size_t)255;
        return p;
    };
    int*   deg  = (int*)  alloc((size_t)N_NODES * 4);
    float* dinv = (float*)alloc((size_t)N_NODES * 4);
    float* coef = (float*)alloc((size_t)N_EDGES * 4);
    float* bufA = (float*)alloc((size_t)N_NODES * 64 * 4);   // h1pre/h1 (w32), Ah2 (w64)
    float* bufB = (float*)alloc((size_t)N_NODES * 128 * 4);  // A*h1pre, A*h1 (w32), h3 (w128)
    float* bufC = (float*)alloc((size_t)N_NODES * 64 * 4);   // h2 (w64)
    float* pool = (float*)alloc((size_t)N_GRAPHS * 128 * 4);
    int*   cnt  = (int*)  alloc((size_t)N_GRAPHS * 4);
    float* zbuf = (float*)alloc((size_t)N_GRAPHS * 64 * 4);

    float* out    = (float*)d_out;
    float* out_mu = out + 10240000;
    float* out_lv = out + 10240000 + 4096;

    hipMemsetAsync(deg, 0, (size_t)N_NODES * 4, stream);
    hipMemsetAsync(pool, 0, (size_t)N_GRAPHS * 128 * 4, stream);
    hipMemsetAsync(cnt, 0, (size_t)N_GRAPHS * 4, stream);

    // norm precompute
    k_count<<<N_EDGES / 256, 256, 0, stream>>>(dstv, deg);
    k_dinv<<<(N_NODES + 255) / 256, 256, 0, stream>>>(deg, dinv);
    k_coef<<<N_EDGES / 256, 256, 0, stream>>>(srcv, dstv, dinv, coef);

    // L1: transform first (x @ [W1m|W1l], no bias), then propagate w32, then bias+relu
    k_dense<64, 16, 0, 64, 0, false><<<N_NODES * 32 / 256, 256, 0, stream>>>(
        x, W1m, b1m, W1l, b1l, bufA);
    k_prop_init<5><<<N_NODES * 32 / 256, 256, 0, stream>>>(bufA, dinv, bufB);
    k_prop_edge<5><<<(size_t)N_EDGES * 32 / 256, 256, 0, stream>>>(srcv, dstv, coef, bufA, bufB);
    k_biasrelu32<<<N_NODES * 32 / 256, 256, 0, stream>>>(bufB, b1m, b1l, bufA);

    // L2: propagate h1 (w32), then dense 16->32 per branch, bias+relu
    k_prop_init<5><<<N_NODES * 32 / 256, 256, 0, stream>>>(bufA, dinv, bufB);
    k_prop_edge<5><<<(size_t)N_EDGES * 32 / 256, 256, 0, stream>>>(srcv, dstv, coef, bufA, bufB);
    k_dense<32, 32, 0, 16, 16, true><<<N_NODES * 64 / 256, 256, 0, stream>>>(
        bufB, W2m, b2m, W2l, b2l, bufC);

    // L3: propagate h2 (w64), then dense 32->64 per branch, bias+relu
    k_prop_init<6><<<N_NODES * 64 / 256, 256, 0, stream>>>(bufC, dinv, bufA);
    k_prop_edge<6><<<(size_t)N_EDGES * 64 / 256, 256, 0, stream>>>(srcv, dstv, coef, bufC, bufA);
    k_dense<64, 64, 0, 32, 32, true><<<N_NODES * 128 / 256, 256, 0, stream>>>(
        bufA, W3m, b3m, W3l, b3l, bufB);

    // mean pool + reparameterize
    k_cnt<<<(N_NODES + 255) / 256, 256, 0, stream>>>(batch, cnt);
    k_pool<<<N_NODES * 128 / 256, 256, 0, stream>>>(bufB, batch, pool);
    k_final<<<16, 256, 0, stream>>>(pool, cnt, eps, zbuf, out_mu, out_lv);

    // decode
    k_decode<<<625, 256, 0, stream>>>(zbuf, Wfc, bfc, out);
}

// Round 4
// 968.282 us; speedup vs baseline: 2.6226x; 2.6226x over previous
//
#include <hip/hip_runtime.h>
#include <hip/hip_bf16.h>

#define N_NODES 100000
#define N_EDGES 3200000
#define N_GRAPHS 64
#define RP_BLOCKS ((N_NODES + 255) / 256)   // 391

__device__ __forceinline__ void atomAddF(float* p, float v) {
    unsafeAtomicAdd(p, v);  // HW global_atomic_add_f32
}

// ---------------- degree / norm precompute ----------------
__global__ void k_count(const int* __restrict__ dst, int* __restrict__ deg) {
    int e = blockIdx.x * 256 + threadIdx.x;
    if (e < N_EDGES) atomicAdd(&deg[dst[e]], 1);
}

__global__ void k_dinv(const int* __restrict__ deg, float* __restrict__ dinv) {
    int i = blockIdx.x * 256 + threadIdx.x;
    if (i < N_NODES) dinv[i] = rsqrtf((float)deg[i] + 1.0f);
}

// ---------------- exclusive scan (3-kernel) for CSR rowptr ----------------
__global__ void k_scan1(const int* __restrict__ deg, int* __restrict__ rowptr,
                        int* __restrict__ bsum) {
    __shared__ int s[256];
    int i = blockIdx.x * 256 + threadIdx.x;
    int v = (i < N_NODES) ? deg[i] : 0;
    s[threadIdx.x] = v;
    __syncthreads();
    for (int off = 1; off < 256; off <<= 1) {
        int t = (threadIdx.x >= off) ? s[threadIdx.x - off] : 0;
        __syncthreads();
        s[threadIdx.x] += t;
        __syncthreads();
    }
    if (i < N_NODES) rowptr[i] = s[threadIdx.x] - v;      // exclusive
    if (threadIdx.x == 255) bsum[blockIdx.x] = s[255];
}

__global__ void k_scan2(int* __restrict__ bsum) {
    __shared__ int s[512];
    int v = (threadIdx.x < RP_BLOCKS) ? bsum[threadIdx.x] : 0;
    s[threadIdx.x] = v;
    __syncthreads();
    for (int off = 1; off < 512; off <<= 1) {
        int t = (threadIdx.x >= off) ? s[threadIdx.x - off] : 0;
        __syncthreads();
        s[threadIdx.x] += t;
        __syncthreads();
    }
    if (threadIdx.x < RP_BLOCKS) bsum[threadIdx.x] = s[threadIdx.x] - v;  // exclusive
}

__global__ void k_scan3(int* __restrict__ rowptr, const int* __restrict__ bsum,
                        int* __restrict__ cursor) {
    int i = blockIdx.x * 256 + threadIdx.x;
    if (i < N_NODES) {
        int r = rowptr[i] + bsum[blockIdx.x];
        rowptr[i] = r;
        cursor[i] = r;
    }
    if (i == 0) rowptr[N_NODES] = N_EDGES;
}

// scatter edges into CSR slots; coef computed here
__global__ void k_fill(const int* __restrict__ src, const int* __restrict__ dst,
                       const float* __restrict__ dinv, int* __restrict__ cursor,
                       int2* __restrict__ csr) {
    int e = blockIdx.x * 256 + threadIdx.x;
    if (e >= N_EDGES) return;
    int s = src[e], t = dst[e];
    float c = dinv[s] * dinv[t];
    int slot = atomicAdd(&cursor[t], 1);
    csr[slot] = make_int2(s, __float_as_int(c));
}

// ---------------- gather propagation: out = Ahat * in (+bias, relu) -------------
// W/4 lanes per node, float4 per lane; self-loop fused; no atomics.
template<int LOGW, bool BIAS_RELU>
__global__ void __launch_bounds__(256) k_gather(
        const int* __restrict__ rowptr, const int2* __restrict__ csr,
        const float* __restrict__ in, const float* __restrict__ dinv,
        const float* __restrict__ ba, const float* __restrict__ bb,
        float* __restrict__ out) {
    constexpr int W4 = (1 << LOGW) / 4;   // lanes per node
    constexpr int NPB = 256 / W4;         // nodes per block
    int n = blockIdx.x * NPB + (threadIdx.x / W4);
    int sub = threadIdx.x % W4;
    const float4* in4 = (const float4*)in;
    float di = dinv[n];
    float selfc = di * di;
    float4 a = in4[n * W4 + sub];
    float4 acc = make_float4(a.x * selfc, a.y * selfc, a.z * selfc, a.w * selfc);
    int j = rowptr[n], end = rowptr[n + 1];
    for (; j < end; ++j) {
        int2 sc = csr[j];
        float c = __int_as_float(sc.y);
        float4 v = in4[sc.x * W4 + sub];
        acc.x = fmaf(v.x, c, acc.x);
        acc.y = fmaf(v.y, c, acc.y);
        acc.z = fmaf(v.z, c, acc.z);
        acc.w = fmaf(v.w, c, acc.w);
    }
    if (BIAS_RELU) {
        constexpr int H = (1 << LOGW) / 2;
        int d = sub * 4;                               // 4 | H, so one half per lane
        const float* bp = (d < H) ? (ba + d) : (bb + d - H);
        acc.x = fmaxf(acc.x + bp[0], 0.0f);
        acc.y = fmaxf(acc.y + bp[1], 0.0f);
        acc.z = fmaxf(acc.z + bp[2], 0.0f);
        acc.w = fmaxf(acc.w + bp[3], 0.0f);
    }
    ((float4*)out)[n * W4 + sub] = acc;
}

// ---------------- dense: two-branch small matmul ----------------
template<int IN_W, int OUT_HALF, int A_OFF, int A_W, int B_OFF, bool BR>
__global__ void k_dense(const float* __restrict__ in,
                        const float* __restrict__ Wa, const float* __restrict__ ba,
                        const float* __restrict__ Wb, const float* __restrict__ bb,
                        float* __restrict__ out) {
    __shared__ float sWa[A_W * OUT_HALF];
    __shared__ float sWb[A_W * OUT_HALF];
    __shared__ float sba[OUT_HALF];
    __shared__ float sbb[OUT_HALF];
    for (int t = threadIdx.x; t < A_W * OUT_HALF; t += 256) {
        sWa[t] = Wa[t];
        sWb[t] = Wb[t];
    }
    if (BR && threadIdx.x < OUT_HALF) {
        sba[threadIdx.x] = ba[threadIdx.x];
        sbb[threadIdx.x] = bb[threadIdx.x];
    }
    __syncthreads();
    const int OUT2 = 2 * OUT_HALF;
    int idx = blockIdx.x * 256 + threadIdx.x;   // exact grid: N*OUT2
    int n = idx / OUT2;
    int d = idx % OUT2;
    bool isB = d >= OUT_HALF;
    int dd = isB ? d - OUT_HALF : d;
    int ko = isB ? B_OFF : A_OFF;
    const float* sW = isB ? sWb : sWa;
    float acc = BR ? (isB ? sbb[dd] : sba[dd]) : 0.0f;
    const float* row = in + n * IN_W;
    #pragma unroll
    for (int k = 0; k < A_W; ++k)
        acc += row[ko + k] * sW[k * OUT_HALF + dd];
    out[idx] = BR ? fmaxf(acc, 0.0f) : acc;
}

// ---------------- pooling (segment reduce; batch is sorted) ----------------
__global__ void k_pool2(const float* __restrict__ h3, const int* __restrict__ batch,
                        float* __restrict__ pool, int* __restrict__ cnt) {
    int g = blockIdx.x >> 2;
    int q = blockIdx.x & 3;
    __shared__ int sb[2];
    if (threadIdx.x < 2) {
        int target = g + threadIdx.x;
        int lo = 0, hi = N_NODES;
        while (lo < hi) {
            int mid = (lo + hi) >> 1;
            if (batch[mid] < target) lo = mid + 1; else hi = mid;
        }
        sb[threadIdx.x] = lo;
    }
    __syncthreads();
    int start = sb[0], end = sb[1];
    int d = threadIdx.x & 127;
    int half = threadIdx.x >> 7;
    float acc = 0.0f;
    for (int n = start + q * 2 + half; n < end; n += 8)
        acc += h3[n * 128 + d];
    __shared__ float sred[256];
    sred[threadIdx.x] = acc;
    __syncthreads();
    if (half == 0)
        atomAddF(&pool[g * 128 + d], sred[threadIdx.x] + sred[threadIdx.x + 128]);
    if (threadIdx.x == 0 && q == 0) cnt[g] = end - start;
}

__global__ void k_final(const float* __restrict__ pool, const int* __restrict__ cnt,
                        const float* __restrict__ eps, float* __restrict__ zbuf,
                        float* __restrict__ out_mu, float* __restrict__ out_lv) {
    int idx = blockIdx.x * 256 + threadIdx.x;   // 4096 threads
    int g = idx >> 6;
    float c = fmaxf((float)cnt[g], 1.0f);
    float mu = pool[g * 128 + (idx & 63)] / c;
    float lv = pool[g * 128 + 64 + (idx & 63)] / c;
    zbuf[idx] = mu + eps[idx] * __expf(0.5f * lv);
    out_mu[idx] = mu;
    out_lv[idx] = lv;
}

// ---------------- decode: sigmoid(z @ Wfc + bfc) ----------------
__global__ void __launch_bounds__(256) k_decode(const float* __restrict__ zbuf,
                                                const float* __restrict__ Wfc,
                                                const float* __restrict__ bfc,
                                                float* __restrict__ out) {
    __shared__ float sz[64 * 64];
    for (int t = threadIdx.x; t < 4096; t += 256) sz[t] = zbuf[t];
    __syncthreads();
    int j = blockIdx.x * 256 + threadIdx.x;     // 625 blocks exact -> 160000
    float bias = bfc[j];
    float acc[64];
    #pragma unroll
    for (int g = 0; g < 64; ++g) acc[g] = bias;
    #pragma unroll 4
    for (int k4 = 0; k4 < 16; ++k4) {
        float w0 = Wfc[(k4 * 4 + 0) * 160000 + j];
        float w1 = Wfc[(k4 * 4 + 1) * 160000 + j];
        float w2 = Wfc[(k4 * 4 + 2) * 160000 + j];
        float w3 = Wfc[(k4 * 4 + 3) * 160000 + j];
        #pragma unroll
        for (int g = 0; g < 64; ++g) {
            float4 zv = *(const float4*)&sz[g * 64 + k4 * 4];
            acc[g] = fmaf(zv.x, w0, acc[g]);
            acc[g] = fmaf(zv.y, w1, acc[g]);
            acc[g] = fmaf(zv.z, w2, acc[g]);
            acc[g] = fmaf(zv.w, w3, acc[g]);
        }
    }
    #pragma unroll
    for (int g = 0; g < 64; ++g) {
        float s = 1.0f / (1.0f + __expf(-acc[g]));
        out[g * 160000 + j] = s;
    }
}

extern "C" void kernel_launch(void* const* d_in, const int* in_sizes, int n_in,
                              void* d_out, int out_size, void* d_ws, size_t ws_size,
                              hipStream_t stream) {
    const float* x     = (const float*)d_in[0];
    const int*   ei    = (const int*)d_in[1];
    const int*   batch = (const int*)d_in[2];
    const float *W1m = (const float*)d_in[3],  *b1m = (const float*)d_in[4];
    const float *W2m = (const float*)d_in[5],  *b2m = (const float*)d_in[6];
    const float *W3m = (const float*)d_in[7],  *b3m = (const float*)d_in[8];
    const float *W1l = (const float*)d_in[9],  *b1l = (const float*)d_in[10];
    const float *W2l = (const float*)d_in[11], *b2l = (const float*)d_in[12];
    const float *W3l = (const float*)d_in[13], *b3l = (const float*)d_in[14];
    const float *Wfc = (const float*)d_in[15], *bfc = (const float*)d_in[16];
    const float *eps = (const float*)d_in[17];

    const int* srcv = ei;
    const int* dstv = ei + N_EDGES;

    char* w = (char*)d_ws;
    auto alloc = [&](size_t bytes) -> char* {
        char* p = w;
        w += (bytes + 255) & ~(size_t)255;
        return p;
    };
    int*   deg    = (int*)  alloc((size_t)N_NODES * 4);
    float* dinv   = (float*)alloc((size_t)N_NODES * 4);
    int*   rowptr = (int*)  alloc((size_t)(N_NODES + 1) * 4);
    int*   cursor = (int*)  alloc((size_t)N_NODES * 4);
    int*   bsum   = (int*)  alloc((size_t)RP_BLOCKS * 4);
    float* pool   = (float*)alloc((size_t)N_GRAPHS * 128 * 4);
    int*   cnt    = (int*)  alloc((size_t)N_GRAPHS * 4);
    float* zbuf   = (float*)alloc((size_t)N_GRAPHS * 64 * 4);
    // Feature arena with lifetime aliasing (total 76.8 MB):
    //   A    : N*64 floats — P1=xW(w32) -> P2=A*h1(w32) -> P3=A*h2(w64)
    //   B    : N*64 floats — h1(w32) -> h2(w64)
    //   csr  : N_EDGES int2 (25.6 MB) — dead after last gather
    //   h3   : N*128 floats — aliases B+csr (both dead at dense3)
    float* arena = (float*)alloc((size_t)N_NODES * 192 * 4);
    float* A   = arena;
    float* B   = arena + (size_t)N_NODES * 64;
    int2*  csr = (int2*)(arena + (size_t)N_NODES * 128);
    float* h3  = B;     // spans B .. end of csr

    float* out    = (float*)d_out;
    float* out_mu = out + 10240000;
    float* out_lv = out + 10240000 + 4096;

    hipMemsetAsync(deg, 0, (size_t)N_NODES * 4, stream);
    hipMemsetAsync(pool, 0, (size_t)N_GRAPHS * 128 * 4, stream);

    // ---- CSR build ----
    k_count<<<N_EDGES / 256, 256, 0, stream>>>(dstv, deg);
    k_dinv<<<(N_NODES + 255) / 256, 256, 0, stream>>>(deg, dinv);
    k_scan1<<<RP_BLOCKS, 256, 0, stream>>>(deg, rowptr, bsum);
    k_scan2<<<1, 512, 0, stream>>>(bsum);
    k_scan3<<<RP_BLOCKS, 256, 0, stream>>>(rowptr, bsum, cursor);
    k_fill<<<N_EDGES / 256, 256, 0, stream>>>(srcv, dstv, dinv, cursor, csr);

    // ---- L1: dense (x @ [W1m|W1l], no bias) -> gather w32 (+bias+relu fused) ----
    k_dense<64, 16, 0, 64, 0, false><<<N_NODES * 32 / 256, 256, 0, stream>>>(
        x, W1m, b1m, W1l, b1l, A);                          // A = P1 = xW (w32)
    k_gather<5, true><<<N_NODES / 32, 256, 0, stream>>>(
        rowptr, csr, A, dinv, b1m, b1l, B);                 // B = h1 (w32)

    // ---- L2: gather w32 -> dense 16->32 x2 (+bias+relu) ----
    k_gather<5, false><<<N_NODES / 32, 256, 0, stream>>>(
        rowptr, csr, B, dinv, b1m, b1l, A);                 // A = P2 = A*h1 (w32)
    k_dense<32, 32, 0, 16, 16, true><<<N_NODES * 64 / 256, 256, 0, stream>>>(
        A, W2m, b2m, W2l, b2l, B);                          // B = h2 (w64)

    // ---- L3: gather w64 -> dense 32->64 x2 (+bias+relu) ----
    k_gather<6, false><<<N_NODES / 16, 256, 0, stream>>>(
        rowptr, csr, B, dinv, b1m, b1l, A);                 // A = P3 = A*h2 (w64)
    k_dense<64, 64, 0, 32, 32, true><<<N_NODES * 128 / 256, 256, 0, stream>>>(
        A, W3m, b3m, W3l, b3l, h3);                         // h3 (w128), over B+csr

    // ---- mean pool (segment reduce) + reparameterize ----
    k_pool2<<<N_GRAPHS * 4, 256, 0, stream>>>(h3, batch, pool, cnt);
    k_final<<<16, 256, 0, stream>>>(pool, cnt, eps, zbuf, out_mu, out_lv);

    // ---- decode ----
    k_decode<<<625, 256, 0, stream>>>(zbuf, Wfc, bfc, out);
}

// Round 5
// 653.954 us; speedup vs baseline: 3.8832x; 1.4807x over previous
//
#include <hip/hip_runtime.h>
#include <hip/hip_bf16.h>

#define N_NODES 100000
#define N_EDGES 3200000
#define N_GRAPHS 64
#define NB 391                 // dst-buckets of 256 nodes (last has 160)
#define KCH 8192               // edges per binning block
#define NCHUNK ((N_EDGES + KCH - 1) / KCH)   // 391
#define MAXBKT 10240           // passB staging capacity (mean 8192, sigma ~90)

__device__ __forceinline__ void atomAddF(float* p, float v) {
    unsafeAtomicAdd(p, v);
}

// ---------------- CSR build: two-level binning ----------------
// pass 0: per-bucket counts
__global__ __launch_bounds__(512) void k_binCount(const int* __restrict__ dst,
                                                  int* __restrict__ gcount) {
    __shared__ int hist[NB];
    for (int t = threadIdx.x; t < NB; t += 512) hist[t] = 0;
    __syncthreads();
    int base = blockIdx.x * KCH;
    int cnt = min(KCH, N_EDGES - base);
    for (int i = threadIdx.x; i < cnt; i += 512)
        atomicAdd(&hist[dst[base + i] >> 8], 1);
    __syncthreads();
    for (int t = threadIdx.x; t < NB; t += 512)
        if (hist[t]) atomicAdd(&gcount[t], hist[t]);
}

// scan bucket counts -> gbase (exclusive), gcursor copy; set rowptr[N]
__global__ __launch_bounds__(512) void k_scanB(const int* __restrict__ gcount,
                                               int* __restrict__ gbase,
                                               int* __restrict__ gcursor,
                                               int* __restrict__ rowptr) {
    __shared__ int s[512];
    int v = (threadIdx.x < NB) ? gcount[threadIdx.x] : 0;
    s[threadIdx.x] = v;
    __syncthreads();
    for (int off = 1; off < 512; off <<= 1) {
        int t = (threadIdx.x >= off) ? s[threadIdx.x - off] : 0;
        __syncthreads();
        s[threadIdx.x] += t;
        __syncthreads();
    }
    if (threadIdx.x < NB) {
        int e = s[threadIdx.x] - v;
        gbase[threadIdx.x] = e;
        gcursor[threadIdx.x] = e;
    }
    if (threadIdx.x == 0) rowptr[N_NODES] = N_EDGES;
}

// pass A: bucket-order 8192 staged edges in LDS, write packed entries coalesced
__global__ __launch_bounds__(512) void k_binA(const int* __restrict__ src,
                                              const int* __restrict__ dst,
                                              int* __restrict__ gcursor,
                                              int* __restrict__ binned) {
    __shared__ int hist[512];
    __shared__ int sc[512];
    __shared__ int sexc[512];
    __shared__ int rbase[512];
    __shared__ int stage[KCH];      // 32 KB
    hist[threadIdx.x] = 0;
    __syncthreads();
    int base = blockIdx.x * KCH;
    int cnt = min(KCH, N_EDGES - base);
    int myb[16], mypos[16];
    int nmine = 0;
    for (int i = 0; i < 16; ++i) {
        int idx = i * 512 + threadIdx.x;
        if (idx < cnt) {
            int b = dst[base + idx] >> 8;
            myb[nmine] = b;
            mypos[nmine] = atomicAdd(&hist[b], 1);
            ++nmine;
        }
    }
    __syncthreads();
    int v = hist[threadIdx.x];
    sc[threadIdx.x] = v;
    __syncthreads();
    for (int off = 1; off < 512; off <<= 1) {
        int t = (threadIdx.x >= off) ? sc[threadIdx.x - off] : 0;
        __syncthreads();
        sc[threadIdx.x] += t;
        __syncthreads();
    }
    sexc[threadIdx.x] = sc[threadIdx.x] - v;    // exclusive bucket start
    __syncthreads();
    if (threadIdx.x < NB && v > 0)
        rbase[threadIdx.x] = atomicAdd(&gcursor[threadIdx.x], v);
    // stage entries grouped by bucket
    for (int k = 0; k < nmine; ++k) {
        int e = base + k * 512 + threadIdx.x;
        int p = ((dst[e] & 255) << 24) | src[e];
        stage[sexc[myb[k]] + mypos[k]] = p;
    }
    __syncthreads();
    // coalesced write-out (binary search bucket of j)
    for (int j = threadIdx.x; j < cnt; j += 512) {
        int lo = 0, hi = NB - 1;
        while (lo < hi) {
            int mid = (lo + hi + 1) >> 1;
            if (sexc[mid] <= j) lo = mid; else hi = mid - 1;
        }
        binned[rbase[lo] + (j - sexc[lo])] = stage[j];
    }
}

// pass B: per-bucket in-place node sort; emits rowptr + dinv too
__global__ __launch_bounds__(512) void k_passB(const int* __restrict__ gbase,
                                               int* __restrict__ csr,
                                               int* __restrict__ rowptr,
                                               float* __restrict__ dinv) {
    int b = blockIdx.x;
    int rb = gbase[b];
    int re = (b == NB - 1) ? N_EDGES : gbase[b + 1];
    int cnt = re - rb;
    int nbase = b << 8;
    int nn = min(nbase + 256, N_NODES) - nbase;
    __shared__ int stage[MAXBKT];   // 40 KB
    __shared__ int nhist[256];
    __shared__ int sc[256];
    __shared__ int ncur[256];
    for (int t = threadIdx.x; t < 256; t += 512) nhist[t] = 0;
    __syncthreads();
    for (int j = threadIdx.x; j < cnt; j += 512) {
        int p = csr[rb + j];
        stage[j] = p;
        atomicAdd(&nhist[((unsigned)p) >> 24], 1);
    }
    __syncthreads();
    if (threadIdx.x < 256) sc[threadIdx.x] = nhist[threadIdx.x];
    __syncthreads();
    for (int off = 1; off < 256; off <<= 1) {
        int t = (threadIdx.x < 256 && threadIdx.x >= off) ? sc[threadIdx.x - off] : 0;
        __syncthreads();
        if (threadIdx.x < 256) sc[threadIdx.x] += t;
        __syncthreads();
    }
    if (threadIdx.x < 256) {
        int e = sc[threadIdx.x] - nhist[threadIdx.x];
        ncur[threadIdx.x] = e;
        if (threadIdx.x < nn) {
            rowptr[nbase + threadIdx.x] = rb + e;
            dinv[nbase + threadIdx.x] = rsqrtf((float)nhist[threadIdx.x] + 1.0f);
        }
    }
    __syncthreads();
    for (int j = threadIdx.x; j < cnt; j += 512) {
        int p = stage[j];
        int slot = atomicAdd(&ncur[((unsigned)p) >> 24], 1);
        csr[rb + slot] = p;     // 4B writes confined to this block's region
    }
}

// ---------------- gather propagation: out = Ahat * in (+bias, relu) -------------
template<int LOGW, bool BIAS_RELU>
__global__ void __launch_bounds__(256) k_gather(
        const int* __restrict__ rowptr, const int* __restrict__ csr,
        const float* __restrict__ in, const float* __restrict__ dinv,
        const float* __restrict__ ba, const float* __restrict__ bb,
        float* __restrict__ out) {
    constexpr int W4 = (1 << LOGW) / 4;
    constexpr int NPB = 256 / W4;
    int n = blockIdx.x * NPB + (threadIdx.x / W4);
    int sub = threadIdx.x % W4;
    const float4* in4 = (const float4*)in;
    float di = dinv[n];
    float selfc = di * di;
    float4 a = in4[n * W4 + sub];
    float4 acc = make_float4(a.x * selfc, a.y * selfc, a.z * selfc, a.w * selfc);
    int j = rowptr[n], end = rowptr[n + 1];
    for (; j < end; ++j) {
        int s = csr[j] & 0xFFFFFF;
        float c = dinv[s] * di;
        float4 v = in4[s * W4 + sub];
        acc.x = fmaf(v.x, c, acc.x);
        acc.y = fmaf(v.y, c, acc.y);
        acc.z = fmaf(v.z, c, acc.z);
        acc.w = fmaf(v.w, c, acc.w);
    }
    if (BIAS_RELU) {
        constexpr int H = (1 << LOGW) / 2;
        int d = sub * 4;
        const float* bp = (d < H) ? (ba + d) : (bb + d - H);
        acc.x = fmaxf(acc.x + bp[0], 0.0f);
        acc.y = fmaxf(acc.y + bp[1], 0.0f);
        acc.z = fmaxf(acc.z + bp[2], 0.0f);
        acc.w = fmaxf(acc.w + bp[3], 0.0f);
    }
    ((float4*)out)[n * W4 + sub] = acc;
}

// ---------------- dense: two-branch matmul, 4 outputs/thread ----------------
template<int IN_W, int OUT_HALF, int A_OFF, int A_W, int B_OFF, bool BR>
__global__ void k_dense4(const float* __restrict__ in,
                         const float* __restrict__ Wa, const float* __restrict__ ba,
                         const float* __restrict__ Wb, const float* __restrict__ bb,
                         float* __restrict__ out) {
    __shared__ float sWa[A_W * OUT_HALF];
    __shared__ float sWb[A_W * OUT_HALF];
    __shared__ float sba[OUT_HALF];
    __shared__ float sbb[OUT_HALF];
    for (int t = threadIdx.x; t < A_W * OUT_HALF; t += 256) {
        sWa[t] = Wa[t];
        sWb[t] = Wb[t];
    }
    if (BR && threadIdx.x < OUT_HALF) {
        sba[threadIdx.x] = ba[threadIdx.x];
        sbb[threadIdx.x] = bb[threadIdx.x];
    }
    __syncthreads();
    constexpr int TPN = OUT_HALF / 2;            // threads per node (OUT2/4)
    int idx = blockIdx.x * 256 + threadIdx.x;    // exact grid: N*TPN
    int n = idx / TPN;
    int q = idx % TPN;
    bool isB = (q * 4) >= OUT_HALF;
    int dd = q * 4 - (isB ? OUT_HALF : 0);
    const float* sW = isB ? sWb : sWa;
    int ko = isB ? B_OFF : A_OFF;
    float4 acc;
    if (BR) {
        const float* bp = isB ? (sbb + dd) : (sba + dd);
        acc = make_float4(bp[0], bp[1], bp[2], bp[3]);
    } else {
        acc = make_float4(0.f, 0.f, 0.f, 0.f);
    }
    const float* row = in + (size_t)n * IN_W + ko;
    #pragma unroll
    for (int k = 0; k < A_W; ++k) {
        float r = row[k];
        float4 wv = *(const float4*)&sW[k * OUT_HALF + dd];
        acc.x = fmaf(r, wv.x, acc.x);
        acc.y = fmaf(r, wv.y, acc.y);
        acc.z = fmaf(r, wv.z, acc.z);
        acc.w = fmaf(r, wv.w, acc.w);
    }
    if (BR) {
        acc.x = fmaxf(acc.x, 0.f); acc.y = fmaxf(acc.y, 0.f);
        acc.z = fmaxf(acc.z, 0.f); acc.w = fmaxf(acc.w, 0.f);
    }
    ((float4*)out)[idx] = acc;
}

// ---------------- pooling (segment reduce; batch is sorted) ----------------
__global__ void k_pool2(const float* __restrict__ h3, const int* __restrict__ batch,
                        float* __restrict__ pool, int* __restrict__ cnt) {
    int g = blockIdx.x >> 2;
    int q = blockIdx.x & 3;
    __shared__ int sb[2];
    if (threadIdx.x < 2) {
        int target = g + threadIdx.x;
        int lo = 0, hi = N_NODES;
        while (lo < hi) {
            int mid = (lo + hi) >> 1;
            if (batch[mid] < target) lo = mid + 1; else hi = mid;
        }
        sb[threadIdx.x] = lo;
    }
    __syncthreads();
    int start = sb[0], end = sb[1];
    int d = threadIdx.x & 127;
    int half = threadIdx.x >> 7;
    float acc = 0.0f;
    for (int n = start + q * 2 + half; n < end; n += 8)
        acc += h3[(size_t)n * 128 + d];
    __shared__ float sred[256];
    sred[threadIdx.x] = acc;
    __syncthreads();
    if (half == 0)
        atomAddF(&pool[g * 128 + d], sred[threadIdx.x] + sred[threadIdx.x + 128]);
    if (threadIdx.x == 0 && q == 0) cnt[g] = end - start;
}

__global__ void k_final(const float* __restrict__ pool, const int* __restrict__ cnt,
                        const float* __restrict__ eps, float* __restrict__ zbuf,
                        float* __restrict__ out_mu, float* __restrict__ out_lv) {
    int idx = blockIdx.x * 256 + threadIdx.x;
    int g = idx >> 6;
    float c = fmaxf((float)cnt[g], 1.0f);
    float mu = pool[g * 128 + (idx & 63)] / c;
    float lv = pool[g * 128 + 64 + (idx & 63)] / c;
    zbuf[idx] = mu + eps[idx] * __expf(0.5f * lv);
    out_mu[idx] = mu;
    out_lv[idx] = lv;
}

// ---------------- decode: sigmoid(z @ Wfc + bfc) ----------------
__global__ void __launch_bounds__(256) k_decode(const float* __restrict__ zbuf,
                                                const float* __restrict__ Wfc,
                                                const float* __restrict__ bfc,
                                                float* __restrict__ out) {
    __shared__ float sz[64 * 64];
    for (int t = threadIdx.x; t < 4096; t += 256) sz[t] = zbuf[t];
    __syncthreads();
    int j = blockIdx.x * 256 + threadIdx.x;
    float bias = bfc[j];
    float acc[64];
    #pragma unroll
    for (int g = 0; g < 64; ++g) acc[g] = bias;
    #pragma unroll 4
    for (int k4 = 0; k4 < 16; ++k4) {
        float w0 = Wfc[(k4 * 4 + 0) * 160000 + j];
        float w1 = Wfc[(k4 * 4 + 1) * 160000 + j];
        float w2 = Wfc[(k4 * 4 + 2) * 160000 + j];
        float w3 = Wfc[(k4 * 4 + 3) * 160000 + j];
        #pragma unroll
        for (int g = 0; g < 64; ++g) {
            float4 zv = *(const float4*)&sz[g * 64 + k4 * 4];
            acc[g] = fmaf(zv.x, w0, acc[g]);
            acc[g] = fmaf(zv.y, w1, acc[g]);
            acc[g] = fmaf(zv.z, w2, acc[g]);
            acc[g] = fmaf(zv.w, w3, acc[g]);
        }
    }
    #pragma unroll
    for (int g = 0; g < 64; ++g) {
        float s = 1.0f / (1.0f + __expf(-acc[g]));
        out[g * 160000 + j] = s;
    }
}

extern "C" void kernel_launch(void* const* d_in, const int* in_sizes, int n_in,
                              void* d_out, int out_size, void* d_ws, size_t ws_size,
                              hipStream_t stream) {
    const float* x     = (const float*)d_in[0];
    const int*   ei    = (const int*)d_in[1];
    const int*   batch = (const int*)d_in[2];
    const float *W1m = (const float*)d_in[3],  *b1m = (const float*)d_in[4];
    const float *W2m = (const float*)d_in[5],  *b2m = (const float*)d_in[6];
    const float *W3m = (const float*)d_in[7],  *b3m = (const float*)d_in[8];
    const float *W1l = (const float*)d_in[9],  *b1l = (const float*)d_in[10];
    const float *W2l = (const float*)d_in[11], *b2l = (const float*)d_in[12];
    const float *W3l = (const float*)d_in[13], *b3l = (const float*)d_in[14];
    const float *Wfc = (const float*)d_in[15], *bfc = (const float*)d_in[16];
    const float *eps = (const float*)d_in[17];

    const int* srcv = ei;
    const int* dstv = ei + N_EDGES;

    char* w = (char*)d_ws;
    auto alloc = [&](size_t bytes) -> char* {
        char* p = w;
        w += (bytes + 255) & ~(size_t)255;
        return p;
    };
    int*   gcount = (int*)  alloc((size_t)NB * 4);
    int*   gbase  = (int*)  alloc((size_t)NB * 4);
    int*   gcursor= (int*)  alloc((size_t)NB * 4);
    int*   rowptr = (int*)  alloc((size_t)(N_NODES + 1) * 4);
    float* dinv   = (float*)alloc((size_t)N_NODES * 4);
    float* pool   = (float*)alloc((size_t)N_GRAPHS * 128 * 4);
    int*   cnt    = (int*)  alloc((size_t)N_GRAPHS * 4);
    float* zbuf   = (float*)alloc((size_t)N_GRAPHS * 64 * 4);
    // Arena (76.8 MB): A | B | csr(32N floats worth) | spare(32N)
    //   h3 (N*128 floats) = B..end, aliasing B + csr + spare (all dead at dense3)
    float* arena = (float*)alloc((size_t)N_NODES * 192 * 4);
    float* A   = arena;
    float* B   = arena + (size_t)N_NODES * 64;
    int*   csr = (int*)(arena + (size_t)N_NODES * 128);
    float* h3  = B;

    float* out    = (float*)d_out;
    float* out_mu = out + 10240000;
    float* out_lv = out + 10240000 + 4096;

    hipMemsetAsync(gcount, 0, (size_t)NB * 4, stream);
    hipMemsetAsync(pool, 0, (size_t)N_GRAPHS * 128 * 4, stream);

    // ---- CSR build (binned) ----
    k_binCount<<<NCHUNK, 512, 0, stream>>>(dstv, gcount);
    k_scanB<<<1, 512, 0, stream>>>(gcount, gbase, gcursor, rowptr);
    k_binA<<<NCHUNK, 512, 0, stream>>>(srcv, dstv, gcursor, csr);
    k_passB<<<NB, 512, 0, stream>>>(gbase, csr, rowptr, dinv);

    // ---- L1: dense (x @ [W1m|W1l], no bias) -> gather w32 (+bias+relu) ----
    k_dense4<64, 16, 0, 64, 0, false><<<N_NODES * 8 / 256, 256, 0, stream>>>(
        x, W1m, b1m, W1l, b1l, A);
    k_gather<5, true><<<N_NODES / 32, 256, 0, stream>>>(
        rowptr, csr, A, dinv, b1m, b1l, B);

    // ---- L2: gather w32 -> dense 16->32 x2 ----
    k_gather<5, false><<<N_NODES / 32, 256, 0, stream>>>(
        rowptr, csr, B, dinv, b1m, b1l, A);
    k_dense4<32, 32, 0, 16, 16, true><<<N_NODES * 16 / 256, 256, 0, stream>>>(
        A, W2m, b2m, W2l, b2l, B);

    // ---- L3: gather w64 -> dense 32->64 x2 ----
    k_gather<6, false><<<N_NODES / 16, 256, 0, stream>>>(
        rowptr, csr, B, dinv, b1m, b1l, A);
    k_dense4<64, 64, 0, 32, 32, true><<<N_NODES * 32 / 256, 256, 0, stream>>>(
        A, W3m, b3m, W3l, b3l, h3);

    // ---- mean pool + reparameterize ----
    k_pool2<<<N_GRAPHS * 4, 256, 0, stream>>>(h3, batch, pool, cnt);
    k_final<<<16, 256, 0, stream>>>(pool, cnt, eps, zbuf, out_mu, out_lv);

    // ---- decode ----
    k_decode<<<625, 256, 0, stream>>>(zbuf, Wfc, bfc, out);
}